// Round 5
// baseline (62.873 us; speedup 1.0000x reference)
//
#include <hip/hip_runtime.h>

#define D 64
#define K 1024
#define HWSZ 1024
#define TPB 256
#define TOKS_PER_BLOCK 64
#define NBLK 1024                      // 65536 / 64
#define QUANT_ELEMS 4194304            // 64*64*32*32
#define TAU_H 1e-3f                    // gap threshold, halved-score domain (== 2e-3 full)

typedef __attribute__((ext_vector_type(8))) short short8;
typedef __attribute__((ext_vector_type(4))) float floatx4;

union Frag { short8 v; unsigned u[4]; };

#define MFMA(a, b, c) __builtin_amdgcn_mfma_f32_16x16x32_bf16((a), (b), (c), 0, 0, 0)

// round f32 -> bf16 (rne), return as f32 bit pattern (low 16 zeroed)
static __device__ inline unsigned bf16_hi_bits(float f) {
    unsigned u = __builtin_bit_cast(unsigned, f);
    return (u + 0x7fffu + ((u >> 16) & 1u)) & 0xffff0000u;
}

// split (a,b) into bf16 hi pair and bf16 lo (residual) pair, each packed in one u32
static __device__ inline void split2(float a, float b, unsigned& hi, unsigned& lo) {
    unsigned ha = bf16_hi_bits(a);
    unsigned hb = bf16_hi_bits(b);
    hi = hb | (ha >> 16);
    float ra = a - __builtin_bit_cast(float, ha);
    float rb = b - __builtin_bit_cast(float, hb);
    lo = bf16_hi_bits(rb) | (bf16_hi_bits(ra) >> 16);
}

// ---------------- prep: codebook -> MFMA B-frag layout (hi/lo) + 0.5||e||^2 ----------------
// G[(tile*4+frag)*64+lane], frag in {h_kh0, h_kh1, l_kh0, l_kh1}
// B lane mapping: code = lane&15, k = (lane>>4)*8 + j, d = kh*32 + k
__global__ void vq_prep(const float* __restrict__ emb, double* __restrict__ acc,
                        float* __restrict__ enorm_h, short8* __restrict__ G) {
    const int tid = threadIdx.x;
    const int lane = tid & 63;
    const int w = tid >> 6;
    const int lhi = lane >> 4, llo = lane & 15;
    const int tile = blockIdx.x * 4 + w;
    if (blockIdx.x == 0 && tid == 0) *acc = 0.0;

    const int code = tile * 16 + llo;
    const float* ep = emb + (size_t)code * D + lhi * 8;
    floatx4 e0 = *(const floatx4*)(ep);
    floatx4 e1 = *(const floatx4*)(ep + 4);
    floatx4 e2 = *(const floatx4*)(ep + 32);
    floatx4 e3 = *(const floatx4*)(ep + 36);
    Frag h0, l0, h1, l1;
    split2(e0.x, e0.y, h0.u[0], l0.u[0]); split2(e0.z, e0.w, h0.u[1], l0.u[1]);
    split2(e1.x, e1.y, h0.u[2], l0.u[2]); split2(e1.z, e1.w, h0.u[3], l0.u[3]);
    split2(e2.x, e2.y, h1.u[0], l1.u[0]); split2(e2.z, e2.w, h1.u[1], l1.u[1]);
    split2(e3.x, e3.y, h1.u[2], l1.u[2]); split2(e3.z, e3.w, h1.u[3], l1.u[3]);
    G[((size_t)tile * 4 + 0) * 64 + lane] = h0.v;
    G[((size_t)tile * 4 + 1) * 64 + lane] = h1.v;
    G[((size_t)tile * 4 + 2) * 64 + lane] = l0.v;
    G[((size_t)tile * 4 + 3) * 64 + lane] = l1.v;

    float s = e0.x * e0.x + e0.y * e0.y + e0.z * e0.z + e0.w * e0.w
            + e1.x * e1.x + e1.y * e1.y + e1.z * e1.z + e1.w * e1.w
            + e2.x * e2.x + e2.y * e2.y + e2.z * e2.z + e2.w * e2.w
            + e3.x * e3.x + e3.y * e3.y + e3.z * e3.z + e3.w * e3.w;
    s += __shfl_xor(s, 16);
    s += __shfl_xor(s, 32);
    if (lhi == 0) enorm_h[code] = 0.5f * s;
}

// ---------------- main ----------------
__global__ __launch_bounds__(TPB, 3) void vq_main(const float* __restrict__ x,
                                                  const float* __restrict__ emb,
                                                  const float* __restrict__ enorm_h,
                                                  const short8* __restrict__ G,
                                                  float* __restrict__ out,
                                                  double* __restrict__ loss_acc) {
    const int tid = threadIdx.x;
    const int lane = tid & 63;
    const int w = __builtin_amdgcn_readfirstlane(tid >> 6);  // wave id = code quarter
    const int lhi = lane >> 4, llo = lane & 15;

    __shared__ short8 afrag[4 * 4 * 64];     // [set][frag][lane], 16 KB
    __shared__ float en_lds[K];              // 4 KB
    __shared__ float xnorm_lds[TOKS_PER_BLOCK];
    __shared__ float pm1[4][TOKS_PER_BLOCK];
    __shared__ float pm2[4][TOKS_PER_BLOCK];
    __shared__ int pidx[4][TOKS_PER_BLOCK];
    __shared__ int sfinal[TOKS_PER_BLOCK];
    __shared__ int s_flaglist[TOKS_PER_BLOCK];
    __shared__ int s_nflag;
    __shared__ double rbv[4];
    __shared__ int rbi[4];

    if (tid == 0) s_nflag = 0;

    const int tb = blockIdx.x * TOKS_PER_BLOCK;
    const int bb = tb >> 10;
    const int hwb = tb & 1023;
    const float* xbase = x + (size_t)bb * (D * HWSZ);

    // en: each wave loads its own 256 codes' 0.5||e||^2
#pragma unroll
    for (int j = 0; j < 4; ++j)
        en_lds[w * 256 + j * 64 + lane] = enorm_h[w * 256 + j * 64 + lane];

    // ---- produce set w's A-frags into LDS (each token loaded & split exactly once) ----
    {
        const int hw = hwb + w * 16 + llo;
        float xn = 0.f;
        Frag ah[2], al[2];
#pragma unroll
        for (int kh = 0; kh < 2; ++kh) {
            const float* xp = xbase + (size_t)(kh * 32 + lhi * 8) * HWSZ + hw;
            float v[8];
#pragma unroll
            for (int j = 0; j < 8; ++j) { v[j] = xp[(size_t)j * HWSZ]; xn += v[j] * v[j]; }
#pragma unroll
            for (int p = 0; p < 4; ++p)
                split2(v[2 * p], v[2 * p + 1], ah[kh].u[p], al[kh].u[p]);
        }
        xn += __shfl_xor(xn, 16);
        xn += __shfl_xor(xn, 32);
        if (lhi == 0) xnorm_lds[w * 16 + llo] = xn;
        afrag[(w * 4 + 0) * 64 + lane] = ah[0].v;
        afrag[(w * 4 + 1) * 64 + lane] = ah[1].v;
        afrag[(w * 4 + 2) * 64 + lane] = al[0].v;
        afrag[(w * 4 + 3) * 64 + lane] = al[1].v;
    }
    __syncthreads();

    // ---- pull all 4 token-sets into registers ----
    short8 Ah[4][2], Al[4][2];
#pragma unroll
    for (int s = 0; s < 4; ++s) {
        Ah[s][0] = afrag[(s * 4 + 0) * 64 + lane];
        Ah[s][1] = afrag[(s * 4 + 1) * 64 + lane];
        Al[s][0] = afrag[(s * 4 + 2) * 64 + lane];
        Al[s][1] = afrag[(s * 4 + 3) * 64 + lane];
    }

    float m1[4][4], m2[4][4];
    int bidx_[4][4];
#pragma unroll
    for (int s = 0; s < 4; ++s)
#pragma unroll
        for (int i = 0; i < 4; ++i) { m1[s][i] = 1e30f; m2[s][i] = 1e30f; bidx_[s][i] = 0; }

    // ---- main loop: 16 tiles (wave-private code quarter), reg double-buffered B ----
    const short8* Gw = G + ((size_t)(w * 16) * 4) * 64 + lane;  // wave's first tile, this lane

#define LOADB(B0, B1, B2, B3, t) { \
        const short8* p_ = Gw + (size_t)(t) * 256; \
        B0 = p_[0]; B1 = p_[64]; B2 = p_[128]; B3 = p_[192]; }

#define COMPUTE(B0, B1, B2, B3, t) { \
        const float en_ = en_lds[w * 256 + (t) * 16 + llo]; \
        _Pragma("unroll") \
        for (int s = 0; s < 4; ++s) { \
            floatx4 acc = {0.f, 0.f, 0.f, 0.f}; \
            acc = MFMA(Ah[s][0], B0, acc); \
            acc = MFMA(Ah[s][1], B1, acc); \
            acc = MFMA(Ah[s][0], B2, acc); \
            acc = MFMA(Ah[s][1], B3, acc); \
            acc = MFMA(Al[s][0], B0, acc); \
            acc = MFMA(Al[s][1], B1, acc); \
            _Pragma("unroll") \
            for (int i = 0; i < 4; ++i) { \
                float sc = en_ - acc[i]; \
                float m1o = m1[s][i]; \
                bool c = sc < m1o; \
                m2[s][i] = __builtin_amdgcn_fmed3f(sc, m1o, m2[s][i]); \
                m1[s][i] = c ? sc : m1o; \
                bidx_[s][i] = c ? (t) : bidx_[s][i]; \
            } \
        } }

    short8 b0h0, b0h1, b0l0, b0l1;
    short8 b1h0, b1h1, b1l0, b1l1;
    LOADB(b0h0, b0h1, b0l0, b0l1, 0);
    for (int t = 0; t < 16; t += 2) {
        LOADB(b1h0, b1h1, b1l0, b1l1, t + 1);
        COMPUTE(b0h0, b0h1, b0l0, b0l1, t);
        if (t + 2 < 16) LOADB(b0h0, b0h1, b0l0, b0l1, t + 2);
        COMPUTE(b1h0, b1h1, b1l0, b1l1, t + 1);
    }

    // ---- cross-lane argmin reduce over 16 col-lanes; write per-wave partials ----
#pragma unroll
    for (int s = 0; s < 4; ++s)
#pragma unroll
        for (int i = 0; i < 4; ++i) {
            float a1 = m1[s][i], a2 = m2[s][i];
            int ai = ((w * 16 + bidx_[s][i]) << 4) | llo;
#pragma unroll
            for (int sft = 1; sft < 16; sft <<= 1) {
                float o1 = __shfl_xor(a1, sft);
                float o2 = __shfl_xor(a2, sft);
                int oi = __shfl_xor(ai, sft);
                float big = fmaxf(a1, o1);
                a2 = fminf(fminf(a2, o2), big);
                if (o1 < a1 || (o1 == a1 && oi < ai)) { a1 = o1; ai = oi; }
            }
            if (llo == 0) {
                const int tl = s * 16 + lhi * 4 + i;
                pm1[w][tl] = a1;
                pm2[w][tl] = a2;
                pidx[w][tl] = ai;
            }
        }
    __syncthreads();

    // ---- merge the 4 wave-partials per token (threads 0..63 = wave 0) ----
    if (tid < TOKS_PER_BLOCK) {
        float a1 = pm1[0][tid], a2 = pm2[0][tid];
        int ai = pidx[0][tid];
#pragma unroll
        for (int c = 1; c < 4; ++c) {
            float b1 = pm1[c][tid], b2 = pm2[c][tid];
            int bi2 = pidx[c][tid];
            float nm2 = fminf(fmaxf(a1, b1), fminf(a2, b2));
            if (b1 < a1 || (b1 == a1 && bi2 < ai)) { a1 = b1; ai = bi2; }
            a2 = nm2;
        }
        sfinal[tid] = ai;
        if (a2 - a1 < TAU_H) {
            int p = atomicAdd(&s_nflag, 1);
            s_flaglist[p] = tid;
        }
        // loss: ||x||^2 + 2 * s_min (halved-score domain)
        double lacc = (double)(xnorm_lds[tid] + 2.0f * a1);
        for (int off = 32; off; off >>= 1) lacc += __shfl_xor(lacc, off);
        if (tid == 0) atomicAdd(loss_acc, lacc);
    }
    __syncthreads();

    // ---- rare: fp64 full rescore for near-tie tokens (block-cooperative) ----
    const int nf = s_nflag;
    for (int f = 0; f < nf; ++f) {
        const int t = s_flaglist[f];
        const int tg = tb + t;
        const float* xf = x + (size_t)(tg >> 10) * (D * HWSZ) + (tg & 1023);
        double bv = 1e300;
        int bi = 0x7fffffff;
        for (int kk = tid; kk < K; kk += TPB) {
            const float* ek = emb + (size_t)kk * D;
            double a = 0.0;
#pragma unroll 8
            for (int d = 0; d < D; ++d) {
                double diff = (double)xf[(size_t)d * HWSZ] - (double)ek[d];
                a += diff * diff;
            }
            if (a < bv || (a == bv && kk < bi)) { bv = a; bi = kk; }
        }
        for (int off = 32; off; off >>= 1) {
            double ov = __shfl_down(bv, off);
            int oi = __shfl_down(bi, off);
            if (ov < bv || (ov == bv && oi < bi)) { bv = ov; bi = oi; }
        }
        if (lane == 0) { rbv[w] = bv; rbi[w] = bi; }
        __syncthreads();
        if (tid == 0) {
            double fv = rbv[0];
            int fi = rbi[0];
#pragma unroll
            for (int c = 1; c < 4; ++c)
                if (rbv[c] < fv || (rbv[c] == fv && rbi[c] < fi)) { fv = rbv[c]; fi = rbi[c]; }
            sfinal[t] = fi;
        }
        __syncthreads();
    }

    // ---- epilogue: write quantized (NCHW) ----
    const int hl = tid & 63;          // token-local
    const int dq = tid >> 6;          // d-quarter 0..3
    const int qidx = sfinal[hl];
    const float* eq = emb + (size_t)qidx * D + dq * 16;
    float* op = out + (size_t)bb * (D * HWSZ) + (size_t)(dq * 16) * HWSZ + hwb + hl;
#pragma unroll
    for (int j0 = 0; j0 < 16; j0 += 4) {
        floatx4 e4 = *(const floatx4*)(eq + j0);
        op[(size_t)(j0 + 0) * HWSZ] = e4.x;
        op[(size_t)(j0 + 1) * HWSZ] = e4.y;
        op[(size_t)(j0 + 2) * HWSZ] = e4.z;
        op[(size_t)(j0 + 3) * HWSZ] = e4.w;
    }
}

__global__ void vq_finalize(const double* __restrict__ acc, float* __restrict__ out) {
    out[QUANT_ELEMS] = (float)(1.25 * (*acc) / (double)QUANT_ELEMS);
}

extern "C" void kernel_launch(void* const* d_in, const int* in_sizes, int n_in,
                              void* d_out, int out_size, void* d_ws, size_t ws_size,
                              hipStream_t stream) {
    const float* x = (const float*)d_in[0];
    const float* emb = (const float*)d_in[1];
    float* out = (float*)d_out;
    double* acc = (double*)d_ws;
    float* enorm_h = (float*)((char*)d_ws + 256);
    short8* G = (short8*)((char*)d_ws + 8192);   // 256 KB of B-fragments

    vq_prep<<<16, TPB, 0, stream>>>(emb, acc, enorm_h, G);
    vq_main<<<NBLK, TPB, 0, stream>>>(x, emb, enorm_h, G, out, acc);
    vq_finalize<<<1, 1, 0, stream>>>(acc, out);
}

// Round 6
// 57.071 us; speedup vs baseline: 1.1017x; 1.1017x over previous
//
#include <hip/hip_runtime.h>

#define D 64
#define K 1024
#define HWSZ 1024
#define TPB 512
#define TOKS_PER_BLOCK 256
#define NBLK 256                       // 65536 / 256 = 1 block per CU
#define QUANT_ELEMS 4194304            // 64*64*32*32
#define TAU_H 1e-3f                    // gap threshold, halved-score domain (== 2e-3 full)
#define GROUP 8                        // tiles per staging group (32 KB)
#define NGROUPS 8                      // 64 tiles total

typedef __attribute__((ext_vector_type(8))) short short8;
typedef __attribute__((ext_vector_type(4))) float floatx4;

union Frag { short8 v; unsigned u[4]; };

#define MFMA(a, b, c) __builtin_amdgcn_mfma_f32_16x16x32_bf16((a), (b), (c), 0, 0, 0)

// round f32 -> bf16 (rne), return as f32 bit pattern (low 16 zeroed)
static __device__ inline unsigned bf16_hi_bits(float f) {
    unsigned u = __builtin_bit_cast(unsigned, f);
    return (u + 0x7fffu + ((u >> 16) & 1u)) & 0xffff0000u;
}

// split (a,b) into bf16 hi pair and bf16 lo (residual) pair, each packed in one u32
static __device__ inline void split2(float a, float b, unsigned& hi, unsigned& lo) {
    unsigned ha = bf16_hi_bits(a);
    unsigned hb = bf16_hi_bits(b);
    hi = hb | (ha >> 16);
    float ra = a - __builtin_bit_cast(float, ha);
    float rb = b - __builtin_bit_cast(float, hb);
    lo = bf16_hi_bits(rb) | (bf16_hi_bits(ra) >> 16);
}

// ---------------- prep: codebook -> MFMA B-frag layout (hi/lo) + 0.5||e||^2 ----------------
// G[(tile*4+frag)*64+lane], frag in {h_kh0, h_kh1, l_kh0, l_kh1}
// B lane mapping: code = lane&15, k = (lane>>4)*8 + j, d = kh*32 + k
__global__ void vq_prep(const float* __restrict__ emb, double* __restrict__ acc,
                        float* __restrict__ enorm_h, short8* __restrict__ G) {
    const int tid = threadIdx.x;
    const int lane = tid & 63;
    const int w = tid >> 6;
    const int lhi = lane >> 4, llo = lane & 15;
    const int tile = blockIdx.x * 4 + w;
    if (blockIdx.x == 0 && tid == 0) *acc = 0.0;

    const int code = tile * 16 + llo;
    const float* ep = emb + (size_t)code * D + lhi * 8;
    floatx4 e0 = *(const floatx4*)(ep);
    floatx4 e1 = *(const floatx4*)(ep + 4);
    floatx4 e2 = *(const floatx4*)(ep + 32);
    floatx4 e3 = *(const floatx4*)(ep + 36);
    Frag h0, l0, h1, l1;
    split2(e0.x, e0.y, h0.u[0], l0.u[0]); split2(e0.z, e0.w, h0.u[1], l0.u[1]);
    split2(e1.x, e1.y, h0.u[2], l0.u[2]); split2(e1.z, e1.w, h0.u[3], l0.u[3]);
    split2(e2.x, e2.y, h1.u[0], l1.u[0]); split2(e2.z, e2.w, h1.u[1], l1.u[1]);
    split2(e3.x, e3.y, h1.u[2], l1.u[2]); split2(e3.z, e3.w, h1.u[3], l1.u[3]);
    G[((size_t)tile * 4 + 0) * 64 + lane] = h0.v;
    G[((size_t)tile * 4 + 1) * 64 + lane] = h1.v;
    G[((size_t)tile * 4 + 2) * 64 + lane] = l0.v;
    G[((size_t)tile * 4 + 3) * 64 + lane] = l1.v;

    float s = e0.x * e0.x + e0.y * e0.y + e0.z * e0.z + e0.w * e0.w
            + e1.x * e1.x + e1.y * e1.y + e1.z * e1.z + e1.w * e1.w
            + e2.x * e2.x + e2.y * e2.y + e2.z * e2.z + e2.w * e2.w
            + e3.x * e3.x + e3.y * e3.y + e3.z * e3.z + e3.w * e3.w;
    s += __shfl_xor(s, 16);
    s += __shfl_xor(s, 32);
    if (lhi == 0) enorm_h[code] = 0.5f * s;
}

// ---------------- main: persistent blocks, 1 per CU ----------------
__global__ __launch_bounds__(TPB, 2) void vq_main(const float* __restrict__ x,
                                                  const float* __restrict__ emb,
                                                  const float* __restrict__ enorm_h,
                                                  const short8* __restrict__ G,
                                                  float* __restrict__ out,
                                                  double* __restrict__ loss_acc) {
    const int tid = threadIdx.x;
    const int lane = tid & 63;
    const int w = __builtin_amdgcn_readfirstlane(tid >> 6);  // wave 0..7
    const int lhi = lane >> 4, llo = lane & 15;

    __shared__ short8 fb[2][GROUP * 4 * 64];   // 2 x 32 KB staging
    __shared__ float en_lds[K];                // 4 KB
    __shared__ float xnorm_lds[TOKS_PER_BLOCK];
    __shared__ int sfinal[TOKS_PER_BLOCK];
    __shared__ int s_flaglist[TOKS_PER_BLOCK];
    __shared__ int s_nflag;
    __shared__ double rbv[8];
    __shared__ int rbi[8];
    __shared__ double lred[8];

    if (tid == 0) s_nflag = 0;

    const int tb = blockIdx.x * TOKS_PER_BLOCK;
    const int bb = tb >> 10;                   // batch index (4 blocks per image)
    const int hwb = tb & 1023;
    const float* xbase = x + (size_t)bb * (D * HWSZ);

    // ---- stage group 0 ASAP (fills latency under the A-conversion below) ----
#pragma unroll
    for (int j = 0; j < 4; ++j)
        __builtin_amdgcn_global_load_lds(
            (const __attribute__((address_space(1))) void*)(G + (size_t)j * TPB + tid),
            (__attribute__((address_space(3))) void*)&fb[0][j * TPB + tid],
            16, 0, 0);

    // ---- load & convert this wave's 32 tokens (2 sets of 16), private ----
    // A mapping: row(token) = llo, k = lhi*8 + j, d = kh*32 + k
    short8 Ah[2][2], Al[2][2];
#pragma unroll
    for (int s = 0; s < 2; ++s) {
        const int hw = hwb + w * 32 + s * 16 + llo;
        float xn = 0.f;
        Frag ah[2], al[2];
#pragma unroll
        for (int kh = 0; kh < 2; ++kh) {
            const float* xp = xbase + (size_t)(kh * 32 + lhi * 8) * HWSZ + hw;
            float v[8];
#pragma unroll
            for (int j = 0; j < 8; ++j) { v[j] = xp[(size_t)j * HWSZ]; xn += v[j] * v[j]; }
#pragma unroll
            for (int p = 0; p < 4; ++p)
                split2(v[2 * p], v[2 * p + 1], ah[kh].u[p], al[kh].u[p]);
        }
        xn += __shfl_xor(xn, 16);
        xn += __shfl_xor(xn, 32);
        if (lhi == 0) xnorm_lds[w * 32 + s * 16 + llo] = xn;
        Ah[s][0] = ah[0].v; Ah[s][1] = ah[1].v;
        Al[s][0] = al[0].v; Al[s][1] = al[1].v;
    }

    // 0.5*||e||^2 table
    en_lds[tid] = enorm_h[tid];
    en_lds[tid + 512] = enorm_h[tid + 512];

    float m1[2][4], m2[2][4];
    int bt[2][4];
#pragma unroll
    for (int s = 0; s < 2; ++s)
#pragma unroll
        for (int i = 0; i < 4; ++i) { m1[s][i] = 1e30f; m2[s][i] = 1e30f; bt[s][i] = 0; }

    __syncthreads();   // staging of group 0 complete (implicit vmcnt drain)

    // ---- main loop: 8 groups x 8 tiles; STAGE(g+1) -> compute(g) -> barrier ----
    int cur = 0;
    for (int g = 0; g < NGROUPS; ++g) {
        if (g < NGROUPS - 1) {
            const short8* src = G + (size_t)(g + 1) * (GROUP * 4 * 64);
#pragma unroll
            for (int j = 0; j < 4; ++j)
                __builtin_amdgcn_global_load_lds(
                    (const __attribute__((address_space(1))) void*)(src + (size_t)j * TPB + tid),
                    (__attribute__((address_space(3))) void*)&fb[cur ^ 1][j * TPB + tid],
                    16, 0, 0);
        }
#pragma unroll
        for (int tt = 0; tt < GROUP; ++tt) {
            const int tile = g * GROUP + tt;
            short8 B0 = fb[cur][(tt * 4 + 0) * 64 + lane];   // h kh0
            short8 B1 = fb[cur][(tt * 4 + 1) * 64 + lane];   // h kh1
            short8 B2 = fb[cur][(tt * 4 + 2) * 64 + lane];   // l kh0
            short8 B3 = fb[cur][(tt * 4 + 3) * 64 + lane];   // l kh1
            const float en_ = en_lds[tile * 16 + llo];
#pragma unroll
            for (int s = 0; s < 2; ++s) {
                floatx4 acc = {0.f, 0.f, 0.f, 0.f};
                acc = MFMA(Ah[s][0], B0, acc);
                acc = MFMA(Ah[s][1], B1, acc);
                acc = MFMA(Al[s][0], B0, acc);
                acc = MFMA(Al[s][1], B1, acc);
                acc = MFMA(Ah[s][0], B2, acc);
                acc = MFMA(Ah[s][1], B3, acc);
#pragma unroll
                for (int i = 0; i < 4; ++i) {
                    float sc = en_ - acc[i];               // 0.5||e||^2 - x.e
                    float m1o = m1[s][i];
                    bool c = sc < m1o;
                    m2[s][i] = __builtin_amdgcn_fmed3f(sc, m1o, m2[s][i]);
                    m1[s][i] = c ? sc : m1o;
                    bt[s][i] = c ? tile : bt[s][i];
                }
            }
        }
        __syncthreads();
        cur ^= 1;
    }

    // ---- per-token argmin reduce over the 16 code-lanes (token = lhi*4+i) ----
    double lacc = 0.0;
#pragma unroll
    for (int s = 0; s < 2; ++s)
#pragma unroll
        for (int i = 0; i < 4; ++i) {
            float a1 = m1[s][i], a2 = m2[s][i];
            int ai = (bt[s][i] << 4) | llo;
#pragma unroll
            for (int sft = 1; sft < 16; sft <<= 1) {
                float o1 = __shfl_xor(a1, sft);
                float o2 = __shfl_xor(a2, sft);
                int oi = __shfl_xor(ai, sft);
                float big = fmaxf(a1, o1);
                a2 = fminf(fminf(a2, o2), big);
                if (o1 < a1 || (o1 == a1 && oi < ai)) { a1 = o1; ai = oi; }
            }
            if (llo == 0) {
                const int tl = w * 32 + s * 16 + lhi * 4 + i;
                sfinal[tl] = ai;
                lacc += (double)(xnorm_lds[tl] + 2.0f * a1);   // ||x||^2 + 2*s_min
                if (a2 - a1 < TAU_H) {
                    int p = atomicAdd(&s_nflag, 1);
                    s_flaglist[p] = tl;
                }
            }
        }
    // loss: wave reduce, then block reduce + one atomic
    for (int off = 32; off; off >>= 1) lacc += __shfl_xor(lacc, off);
    if (lane == 0) lred[w] = lacc;
    __syncthreads();
    if (tid == 0) {
        double t = 0.0;
#pragma unroll
        for (int c = 0; c < 8; ++c) t += lred[c];
        atomicAdd(loss_acc, t);
    }

    // ---- rare: fp64 full rescore for near-tie tokens (block-cooperative) ----
    const int nf = s_nflag;
    for (int f = 0; f < nf; ++f) {
        const int t = s_flaglist[f];
        const int tg = tb + t;
        const float* xf = x + (size_t)(tg >> 10) * (D * HWSZ) + (tg & 1023);
        double bv = 1e300;
        int bi = 0x7fffffff;
        for (int kk = tid; kk < K; kk += TPB) {
            const float* ek = emb + (size_t)kk * D;
            double a = 0.0;
#pragma unroll 8
            for (int d = 0; d < D; ++d) {
                double diff = (double)xf[(size_t)d * HWSZ] - (double)ek[d];
                a += diff * diff;
            }
            if (a < bv || (a == bv && kk < bi)) { bv = a; bi = kk; }
        }
        for (int off = 32; off; off >>= 1) {
            double ov = __shfl_down(bv, off);
            int oi = __shfl_down(bi, off);
            if (ov < bv || (ov == bv && oi < bi)) { bv = ov; bi = oi; }
        }
        if (lane == 0) { rbv[w] = bv; rbi[w] = bi; }
        __syncthreads();
        if (tid == 0) {
            double fv = rbv[0];
            int fi = rbi[0];
#pragma unroll
            for (int c = 1; c < 8; ++c)
                if (rbv[c] < fv || (rbv[c] == fv && rbi[c] < fi)) { fv = rbv[c]; fi = rbi[c]; }
            sfinal[t] = fi;
        }
        __syncthreads();
    }

    // ---- epilogue: write quantized (NCHW) ----
    const int hl = tid & 255;          // token-local 0..255
    const int dh = tid >> 8;           // d-half: 0 or 1 (32 dims each)
    const int qidx = sfinal[hl];
    const float* eq = emb + (size_t)qidx * D + dh * 32;
    float* op = out + (size_t)bb * (D * HWSZ) + (size_t)(dh * 32) * HWSZ + hwb + hl;
#pragma unroll
    for (int j0 = 0; j0 < 32; j0 += 4) {
        floatx4 e4 = *(const floatx4*)(eq + j0);
        op[(size_t)(j0 + 0) * HWSZ] = e4.x;
        op[(size_t)(j0 + 1) * HWSZ] = e4.y;
        op[(size_t)(j0 + 2) * HWSZ] = e4.z;
        op[(size_t)(j0 + 3) * HWSZ] = e4.w;
    }
}

__global__ void vq_finalize(const double* __restrict__ acc, float* __restrict__ out) {
    out[QUANT_ELEMS] = (float)(1.25 * (*acc) / (double)QUANT_ELEMS);
}

extern "C" void kernel_launch(void* const* d_in, const int* in_sizes, int n_in,
                              void* d_out, int out_size, void* d_ws, size_t ws_size,
                              hipStream_t stream) {
    const float* x = (const float*)d_in[0];
    const float* emb = (const float*)d_in[1];
    float* out = (float*)d_out;
    double* acc = (double*)d_ws;
    float* enorm_h = (float*)((char*)d_ws + 256);
    short8* G = (short8*)((char*)d_ws + 8192);   // 256 KB of B-fragments

    vq_prep<<<16, 256, 0, stream>>>(emb, acc, enorm_h, G);
    vq_main<<<NBLK, TPB, 0, stream>>>(x, emb, enorm_h, G, out, acc);
    vq_finalize<<<1, 1, 0, stream>>>(acc, out);
}